// Round 1
// baseline (5239.353 us; speedup 1.0000x reference)
//
#include <hip/hip_runtime.h>

// ---------------------------------------------------------------------------
// PAM (parallax attention) forward, MI355X. Round 3: register-block convs
// 2 pixels/thread (rows th, th+8 of a 16x32 tile) to halve per-FMA scalar
// weight-load and staging/barrier overhead.
//
// Shapes: B=2, C=64, 4C=256, H=W=256, WS=8 -> hn=wn=32, P=64, windows=2048.
// d_out = [out_left (2,64,256,256), out_right (2,64,256,256)] fp32 concat.
//
// Reference patchify applied to [b,h,w,c]-ordered gathered tensors via flat
// reinterpretation: element (p,q,c') of window (hn,wn) is at flat offset
// f = c'*65536 + hn*2048 + p*256 + wn*8 + q of the [h,w,c] buffer.
//
// Centering (reference .mean((4,5))): over (q, c) per (b,hn,wn,p) — 512
// elements.
//
// Workspace (floats):
//   [0, 33554432)        y1 (conv1 output, one side at a time);
//                        later aliased: GK@0, GQ@8388608, Gxr@16777216, Gxl@25165824
//   [33554432, 41943040) Q
//   [41943040, 50331648) K
//   [50331648, 50332672) bn stats: [side][scale(256), shift(256)]
// ---------------------------------------------------------------------------

__global__ __launch_bounds__(256) void k_bnstats(
    const float* __restrict__ cat_l, const float* __restrict__ cat_r,
    const float* __restrict__ gamma, const float* __restrict__ beta,
    float* __restrict__ stats)
{
    int ch = blockIdx.x & 255;
    int side = blockIdx.x >> 8;
    const float* src = side ? cat_r : cat_l;
    int tid = threadIdx.x;
    float s = 0.f, s2 = 0.f;
    #pragma unroll
    for (int b = 0; b < 2; ++b) {
        const float* p = src + (size_t)b * 16777216 + (size_t)ch * 65536;
        for (int i = tid; i < 65536; i += 256) {
            float v = p[i];
            s += v; s2 += v * v;
        }
    }
    __shared__ float rs[256], rq[256];
    rs[tid] = s; rq[tid] = s2;
    __syncthreads();
    for (int off = 128; off > 0; off >>= 1) {
        if (tid < off) { rs[tid] += rs[tid + off]; rq[tid] += rq[tid + off]; }
        __syncthreads();
    }
    if (tid == 0) {
        float mean = rs[0] * (1.f / 131072.f);
        float var  = rq[0] * (1.f / 131072.f) - mean * mean;
        float rstd = rsqrtf(var + 1e-5f);
        float sc = gamma[ch] * rstd;
        stats[side * 512 + ch] = sc;
        stats[side * 512 + 256 + ch] = beta[ch] - mean * sc;
    }
}

// Grouped 3x3 conv (groups=4, 64ic -> 64oc per group), BN applied to input on
// the fly, bias + LeakyReLU(0.1) epilogue.
// Tile: 16h x 32w per block; each thread computes rows th and th+8 (2 pixels)
// so one s_load weight batch feeds 18 FMAs and one stage feeds 1152 FMAs/thread.
__global__ __launch_bounds__(256) void k_conv1(
    const float* __restrict__ cat, const float* __restrict__ stats,
    const float* __restrict__ w1, const float* __restrict__ b1,
    float* __restrict__ y1)
{
    int blk = blockIdx.x;
    int wt = blk & 7;   blk >>= 3;
    int ht = blk & 15;  blk >>= 4;
    int g  = blk & 3;   blk >>= 2;
    int b  = blk;
    int tid = threadIdx.x;
    int tw = tid & 31, th = tid >> 5;          // th: 0..7
    int h = ht * 16 + th, w = wt * 32 + tw;    // this thread: rows h and h+8

    __shared__ float tile[18][36];
    float acc0[64], acc1[64];
    #pragma unroll
    for (int oc = 0; oc < 64; ++oc) {
        float bb = b1[g * 64 + oc];
        acc0[oc] = bb; acc1[oc] = bb;
    }

    const float* catg = cat + ((size_t)b * 256 + g * 64) * 65536;
    int h0 = ht * 16 - 1, w0 = wt * 32 - 1;

    for (int ic = 0; ic < 64; ++ic) {
        float sc = stats[g * 64 + ic];
        float sh = stats[256 + g * 64 + ic];
        const float* plane = catg + (size_t)ic * 65536;
        __syncthreads();
        for (int i = tid; i < 612; i += 256) {     // 18 rows x 34 cols halo
            int r = i / 34, cc = i - r * 34;
            int hh = h0 + r, ww = w0 + cc;
            float v = 0.f;
            if ((unsigned)hh < 256u && (unsigned)ww < 256u)
                v = fmaf(plane[hh * 256 + ww], sc, sh);
            tile[r][cc] = v;
        }
        __syncthreads();
        float xv0[9], xv1[9];
        #pragma unroll
        for (int kh = 0; kh < 3; ++kh)
            #pragma unroll
            for (int kw = 0; kw < 3; ++kw) {
                xv0[kh * 3 + kw] = tile[th + kh][tw + kw];
                xv1[kh * 3 + kw] = tile[th + 8 + kh][tw + kw];
            }
        const float* wic = w1 + (size_t)(g * 64) * 576 + (size_t)ic * 9;
        #pragma unroll
        for (int oc = 0; oc < 64; ++oc) {
            const float* wo = wic + (size_t)oc * 576;  // block-uniform -> s_load
            float s0 = acc0[oc], s1 = acc1[oc];
            #pragma unroll
            for (int k = 0; k < 9; ++k) {
                float wv = wo[k];
                s0 = fmaf(wv, xv0[k], s0);
                s1 = fmaf(wv, xv1[k], s1);
            }
            acc0[oc] = s0; acc1[oc] = s1;
        }
    }
    float* yp = y1 + ((size_t)b * 256 + g * 64) * 65536 + h * 256 + w;
    #pragma unroll
    for (int oc = 0; oc < 64; ++oc) {
        float v0 = acc0[oc], v1 = acc1[oc];
        yp[(size_t)oc * 65536]        = v0 > 0.f ? v0 : 0.1f * v0;
        yp[(size_t)oc * 65536 + 2048] = v1 > 0.f ? v1 : 0.1f * v1;  // +8 rows
    }
}

// Grouped 3x3 conv on y1 + bias + BN(cat) residual, then grouped 1x1 (64->16
// per group) producing Q (or K). Never materializes the 256-ch ResB output.
// Same 2-pixel/thread blocking as k_conv1.
__global__ __launch_bounds__(256) void k_conv2(
    const float* __restrict__ y1, const float* __restrict__ cat,
    const float* __restrict__ stats,
    const float* __restrict__ w2, const float* __restrict__ b2,
    const float* __restrict__ pw, const float* __restrict__ pb,
    float* __restrict__ Qout)
{
    int blk = blockIdx.x;
    int wt = blk & 7;   blk >>= 3;
    int ht = blk & 15;  blk >>= 4;
    int g  = blk & 3;   blk >>= 2;
    int b  = blk;
    int tid = threadIdx.x;
    int tw = tid & 31, th = tid >> 5;
    int h = ht * 16 + th, w = wt * 32 + tw;

    __shared__ float tile[18][36];
    float acc0[64], acc1[64];
    #pragma unroll
    for (int oc = 0; oc < 64; ++oc) {
        float bb = b2[g * 64 + oc];
        acc0[oc] = bb; acc1[oc] = bb;
    }

    const float* yg = y1 + ((size_t)b * 256 + g * 64) * 65536;
    int h0 = ht * 16 - 1, w0 = wt * 32 - 1;

    for (int ic = 0; ic < 64; ++ic) {
        const float* plane = yg + (size_t)ic * 65536;
        __syncthreads();
        for (int i = tid; i < 612; i += 256) {
            int r = i / 34, cc = i - r * 34;
            int hh = h0 + r, ww = w0 + cc;
            float v = 0.f;
            if ((unsigned)hh < 256u && (unsigned)ww < 256u)
                v = plane[hh * 256 + ww];
            tile[r][cc] = v;
        }
        __syncthreads();
        float xv0[9], xv1[9];
        #pragma unroll
        for (int kh = 0; kh < 3; ++kh)
            #pragma unroll
            for (int kw = 0; kw < 3; ++kw) {
                xv0[kh * 3 + kw] = tile[th + kh][tw + kw];
                xv1[kh * 3 + kw] = tile[th + 8 + kh][tw + kw];
            }
        const float* wic = w2 + (size_t)(g * 64) * 576 + (size_t)ic * 9;
        #pragma unroll
        for (int oc = 0; oc < 64; ++oc) {
            const float* wo = wic + (size_t)oc * 576;
            float s0 = acc0[oc], s1 = acc1[oc];
            #pragma unroll
            for (int k = 0; k < 9; ++k) {
                float wv = wo[k];
                s0 = fmaf(wv, xv0[k], s0);
                s1 = fmaf(wv, xv1[k], s1);
            }
            acc0[oc] = s0; acc1[oc] = s1;
        }
    }
    // residual: + BN(cat), both rows
    const float* catp = cat + ((size_t)b * 256 + g * 64) * 65536 + h * 256 + w;
    #pragma unroll
    for (int oc = 0; oc < 64; ++oc) {
        float sc = stats[g * 64 + oc];
        float sh = stats[256 + g * 64 + oc];
        acc0[oc] += fmaf(catp[(size_t)oc * 65536], sc, sh);
        acc1[oc] += fmaf(catp[(size_t)oc * 65536 + 2048], sc, sh);
    }
    // grouped 1x1: oq = g*16 + j over this group's 64 channels, both rows
    float* qp = Qout + ((size_t)b * 64 + g * 16) * 65536 + h * 256 + w;
    #pragma unroll
    for (int j = 0; j < 16; ++j) {
        const float* wv = pw + (size_t)(g * 16 + j) * 64;
        float s0 = pb[g * 16 + j], s1 = s0;
        #pragma unroll
        for (int ic2 = 0; ic2 < 64; ++ic2) {
            float wvv = wv[ic2];
            s0 = fmaf(wvv, acc0[ic2], s0);
            s1 = fmaf(wvv, acc1[ic2], s1);
        }
        qp[(size_t)j * 65536]        = s0;
        qp[(size_t)j * 65536 + 2048] = s1;
    }
}

// Horizontal disparity gathers, output in [b,h,w,c] layout (flat-index ready).
__global__ __launch_bounds__(256) void k_gather(
    const float* __restrict__ Kb, const float* __restrict__ Qb,
    const float* __restrict__ xr, const float* __restrict__ xl,
    const int* __restrict__ dl, const int* __restrict__ dr,
    float* __restrict__ GK, float* __restrict__ GQ,
    float* __restrict__ Gxr, float* __restrict__ Gxl)
{
    int blk = blockIdx.x;
    int h = blk & 255; blk >>= 8;
    int b = blk & 1;   blk >>= 1;
    int sel = blk;
    const float* src; float* dst; const int* dd; int r2l;
    if (sel == 0)      { src = Kb; dst = GK;  dd = dl; r2l = 1; }
    else if (sel == 1) { src = Qb; dst = GQ;  dd = dr; r2l = 0; }
    else if (sel == 2) { src = xr; dst = Gxr; dd = dl; r2l = 1; }
    else               { src = xl; dst = Gxl; dd = dr; r2l = 0; }
    const int* drow = dd + ((size_t)b * 256 + h) * 256;
    const float* sp = src + (size_t)b * 4194304 + h * 256;
    float* dp = dst + ((size_t)b * 256 + h) * 16384;
    int tid = threadIdx.x;
    for (int i = tid; i < 16384; i += 256) {
        int w = i >> 6, cc = i & 63;
        int d = drow[w];
        int wi = r2l ? (w - d < 0 ? 0 : w - d) : (w + d > 255 ? 255 : w + d);
        dp[i] = sp[(size_t)cc * 65536 + wi];
    }
}

// Per-window attention: score = patchA @ centered(sel)^T, softmax, @ x_sel,
// unpatchify + masked residual. One block per (dir, b, hn, wn).
__global__ __launch_bounds__(256) void k_attn(
    const float* __restrict__ Qb, const float* __restrict__ Kb,
    const float* __restrict__ GK, const float* __restrict__ GQ,
    const float* __restrict__ Gxr, const float* __restrict__ Gxl,
    const float* __restrict__ xl, const float* __restrict__ xr,
    const int* __restrict__ dl, const int* __restrict__ dr,
    float* __restrict__ out)
{
    int blk = blockIdx.x;
    int wn = blk & 31; blk >>= 5;
    int hn = blk & 31; blk >>= 5;
    int b  = blk & 1;  blk >>= 1;
    int dir = blk;  // 0: out_left, 1: out_right

    const float* Amat = dir ? Kb : Qb;
    const float* Bg   = dir ? GQ : GK;
    const float* Xg   = dir ? Gxl : Gxr;
    const float* base = dir ? xr : xl;
    const int*  dd    = dir ? dr : dl;
    float* op = out + (size_t)dir * 8388608;

    __shared__ float A[64][65];
    __shared__ float Bm[64][65];
    __shared__ float S[64][65];
    __shared__ float rowsum[64];
    __shared__ float pmean[8];

    int tid = threadIdx.x;
    // A[p1][cc] = Amat[b, cc, hn*8+pr, wn*8+qr]   (true patchify)
    size_t abase = (size_t)b * 4194304 + (size_t)(hn * 8) * 256 + wn * 8;
    for (int i = tid; i < 4096; i += 256) {
        int cc = i >> 6, p1 = i & 63;
        A[p1][cc] = Amat[abase + (size_t)cc * 65536 + (p1 >> 3) * 256 + (p1 & 7)];
    }
    // Bm[p2][cc] = G[b, f], f = cc*65536 + hn*2048 + p*256 + wn*8 + q (scrambled)
    size_t gbase = (size_t)b * 4194304 + hn * 2048 + wn * 8;
    for (int i = tid; i < 4096; i += 256) {
        int cc = i >> 6, p2 = i & 63;
        Bm[p2][cc] = Bg[gbase + (size_t)cc * 65536 + (p2 >> 3) * 256 + (p2 & 7)];
    }
    __syncthreads();
    // center: reference means over axes (q, c) per p -> pmean[p] over 512 elems
    if (tid < 64) {
        float s = 0.f;
        #pragma unroll 8
        for (int cc = 0; cc < 64; ++cc) s += Bm[tid][cc];
        rowsum[tid] = s;
    }
    __syncthreads();
    if (tid < 8) {
        float s = 0.f;
        #pragma unroll
        for (int q = 0; q < 8; ++q) s += rowsum[tid * 8 + q];
        pmean[tid] = s * (1.f / 512.f);
    }
    __syncthreads();
    for (int i = tid; i < 4096; i += 256) {
        int p2 = i >> 6, cc = i & 63;
        Bm[p2][cc] -= pmean[p2 >> 3];
    }
    __syncthreads();

    int tp = (tid >> 4) << 2;
    int tc = (tid & 15) << 2;
    {   // S = A @ Bm^T  (4x4 per thread)
        float accs[4][4] = {};
        for (int cc = 0; cc < 64; ++cc) {
            float av[4], bv[4];
            #pragma unroll
            for (int i = 0; i < 4; ++i) av[i] = A[tp + i][cc];
            #pragma unroll
            for (int j = 0; j < 4; ++j) bv[j] = Bm[tc + j][cc];
            #pragma unroll
            for (int i = 0; i < 4; ++i)
                #pragma unroll
                for (int j = 0; j < 4; ++j)
                    accs[i][j] = fmaf(av[i], bv[j], accs[i][j]);
        }
        #pragma unroll
        for (int i = 0; i < 4; ++i)
            #pragma unroll
            for (int j = 0; j < 4; ++j)
                S[tp + i][tc + j] = accs[i][j];
    }
    __syncthreads();
    if (tid < 64) {  // row softmax
        float m = -3.0e38f;
        #pragma unroll 8
        for (int j = 0; j < 64; ++j) m = fmaxf(m, S[tid][j]);
        float ssum = 0.f;
        #pragma unroll 8
        for (int j = 0; j < 64; ++j) {
            float e = __expf(S[tid][j] - m);
            S[tid][j] = e; ssum += e;
        }
        float inv = 1.f / ssum;
        #pragma unroll 8
        for (int j = 0; j < 64; ++j) S[tid][j] *= inv;
    }
    __syncthreads();
    // reload Bm <- x_sel (scrambled)
    for (int i = tid; i < 4096; i += 256) {
        int cc = i >> 6, p2 = i & 63;
        Bm[p2][cc] = Xg[gbase + (size_t)cc * 65536 + (p2 >> 3) * 256 + (p2 & 7)];
    }
    __syncthreads();
    {   // out = S @ X, unpatchify, masked residual
        float accs[4][4] = {};
        for (int p2 = 0; p2 < 64; ++p2) {
            float sv[4], xv[4];
            #pragma unroll
            for (int i = 0; i < 4; ++i) sv[i] = S[tp + i][p2];
            #pragma unroll
            for (int j = 0; j < 4; ++j) xv[j] = Bm[p2][tc + j];
            #pragma unroll
            for (int i = 0; i < 4; ++i)
                #pragma unroll
                for (int j = 0; j < 4; ++j)
                    accs[i][j] = fmaf(sv[i], xv[j], accs[i][j]);
        }
        #pragma unroll
        for (int i = 0; i < 4; ++i) {
            int p1 = tp + i;
            int h1 = hn * 8 + (p1 >> 3), w1 = wn * 8 + (p1 & 7);
            int d = dd[(size_t)b * 65536 + h1 * 256 + w1];
            float msk = dir ? ((w1 + d <= 255) ? 1.f : 0.f)
                            : ((w1 - d >= 0) ? 1.f : 0.f);
            #pragma unroll
            for (int j = 0; j < 4; ++j) {
                int ch = tc + j;
                size_t o = (size_t)b * 4194304 + (size_t)ch * 65536 + (size_t)h1 * 256 + w1;
                op[o] = fmaf(accs[i][j], msk, base[o]);
            }
        }
    }
}

extern "C" void kernel_launch(void* const* d_in, const int* in_sizes, int n_in,
                              void* d_out, int out_size, void* d_ws, size_t ws_size,
                              hipStream_t stream) {
    (void)in_sizes; (void)n_in; (void)out_size; (void)ws_size;
    const float* x_left  = (const float*)d_in[0];
    const float* x_right = (const float*)d_in[1];
    const float* cat_l   = (const float*)d_in[2];
    const float* cat_r   = (const float*)d_in[3];
    const int*   d_left  = (const int*)d_in[4];
    const int*   d_right = (const int*)d_in[5];
    const float* gamma   = (const float*)d_in[6];
    const float* beta    = (const float*)d_in[7];
    const float* rb_w1   = (const float*)d_in[8];
    const float* rb_b1   = (const float*)d_in[9];
    const float* rb_w2   = (const float*)d_in[10];
    const float* rb_b2   = (const float*)d_in[11];
    const float* bq_w    = (const float*)d_in[12];
    const float* bq_b    = (const float*)d_in[13];
    const float* bs_w    = (const float*)d_in[14];
    const float* bs_b    = (const float*)d_in[15];
    float* out = (float*)d_out;
    float* ws  = (float*)d_ws;

    float* y1    = ws;               // 33,554,432 floats (reused per side)
    float* GK    = ws;               // alias after y1 is dead
    float* GQ    = ws + 8388608;
    float* Gxr   = ws + 16777216;
    float* Gxl   = ws + 25165824;
    float* Qb    = ws + 33554432;
    float* Kb    = ws + 41943040;
    float* stats = ws + 50331648;    // [2][scale 256 | shift 256]

    k_bnstats<<<512, 256, 0, stream>>>(cat_l, cat_r, gamma, beta, stats);
    k_conv1<<<1024, 256, 0, stream>>>(cat_l, stats, rb_w1, rb_b1, y1);
    k_conv2<<<1024, 256, 0, stream>>>(y1, cat_l, stats, rb_w2, rb_b2, bq_w, bq_b, Qb);
    k_conv1<<<1024, 256, 0, stream>>>(cat_r, stats + 512, rb_w1, rb_b1, y1);
    k_conv2<<<1024, 256, 0, stream>>>(y1, cat_r, stats + 512, rb_w2, rb_b2, bs_w, bs_b, Kb);
    k_gather<<<2048, 256, 0, stream>>>(Kb, Qb, x_right, x_left, d_left, d_right,
                                       GK, GQ, Gxr, Gxl);
    k_attn<<<4096, 256, 0, stream>>>(Qb, Kb, GK, GQ, Gxr, Gxl,
                                     x_left, x_right, d_left, d_right, out);
}

// Round 2
// 3709.710 us; speedup vs baseline: 1.4123x; 1.4123x over previous
//
#include <hip/hip_runtime.h>

// ---------------------------------------------------------------------------
// PAM (parallax attention) forward, MI355X. Round 4:
//  - conv2's grouped 1x1 folded into the 3x3 weights (16 out-ch instead of 64,
//    3.7x FLOP cut); BN residual folded to pwsc*cat + bias-const.
//  - conv weights staged to LDS (broadcast ds_read) instead of s_load chains.
//  - reg-staged double buffering: issue ic+1 global loads, compute ic, then
//    barrier + LDS write. oc-split 32/block in conv1 for occupancy.
//
// Workspace (floats) — unchanged total:
//   [0, 33554432)        y1 ; later aliased GK@0, GQ@8388608, Gxr@16777216, Gxl@25165824
//   [33554432, 41943040) Q
//   [41943040, 50331648) K   (first 49216 floats used as WfQ/bfQ scratch pre-K)
//   [50331648, 50332672) bn stats: [side][scale(256), shift(256)]
// d_out used as scratch for WfK/bfK until k_attn (last dispatch) writes it.
// ---------------------------------------------------------------------------

__global__ __launch_bounds__(256) void k_bnstats(
    const float* __restrict__ cat_l, const float* __restrict__ cat_r,
    const float* __restrict__ gamma, const float* __restrict__ beta,
    float* __restrict__ stats)
{
    int ch = blockIdx.x & 255;
    int side = blockIdx.x >> 8;
    const float* src = side ? cat_r : cat_l;
    int tid = threadIdx.x;
    float s = 0.f, s2 = 0.f;
    #pragma unroll
    for (int b = 0; b < 2; ++b) {
        const float* p = src + (size_t)b * 16777216 + (size_t)ch * 65536;
        for (int i = tid; i < 65536; i += 256) {
            float v = p[i];
            s += v; s2 += v * v;
        }
    }
    __shared__ float rs[256], rq[256];
    rs[tid] = s; rq[tid] = s2;
    __syncthreads();
    for (int off = 128; off > 0; off >>= 1) {
        if (tid < off) { rs[tid] += rs[tid + off]; rq[tid] += rq[tid + off]; }
        __syncthreads();
    }
    if (tid == 0) {
        float mean = rs[0] * (1.f / 131072.f);
        float var  = rq[0] * (1.f / 131072.f) - mean * mean;
        float rstd = rsqrtf(var + 1e-5f);
        float sc = gamma[ch] * rstd;
        stats[side * 512 + ch] = sc;
        stats[side * 512 + 256 + ch] = beta[ch] - mean * sc;
    }
}

// Fold grouped 1x1 (pw,pb) into conv2 3x3 weights + BN residual.
// Wf layout: [(g*64+ic)*16 + j] * 12 : [0..8]=Wtilde, [9]=pw[j][ic]*sc[ic], pad.
// bf[g*16+j] = pb + sum_oc pw*(b2 + sh).
__global__ __launch_bounds__(256) void k_fold(
    const float* __restrict__ w2, const float* __restrict__ b2,
    const float* __restrict__ bqw, const float* __restrict__ bqb,
    const float* __restrict__ bsw, const float* __restrict__ bsb,
    const float* __restrict__ stats,
    float* __restrict__ WfQ, float* __restrict__ bfQ,
    float* __restrict__ WfK, float* __restrict__ bfK)
{
    int idx = blockIdx.x * 256 + threadIdx.x;
    int j    = idx & 15;
    int ic   = (idx >> 4) & 63;
    int g    = (idx >> 10) & 3;
    int side = (idx >> 12) & 1;
    const float* pw  = side ? bsw : bqw;
    const float* st  = stats + side * 512;
    const float* pwr = pw + (size_t)(g * 16 + j) * 64;
    const float* wbase = w2 + (size_t)(g * 64) * 576 + ic * 9;
    float a[9] = {0.f,0.f,0.f,0.f,0.f,0.f,0.f,0.f,0.f};
    #pragma unroll 4
    for (int oc = 0; oc < 64; ++oc) {
        float p = pwr[oc];
        const float* wrow = wbase + (size_t)oc * 576;
        #pragma unroll
        for (int k = 0; k < 9; ++k) a[k] = fmaf(p, wrow[k], a[k]);
    }
    float* dst = (side ? WfK : WfQ) + (size_t)((g * 64 + ic) * 16 + j) * 12;
    #pragma unroll
    for (int k = 0; k < 9; ++k) dst[k] = a[k];
    dst[9]  = pwr[ic] * st[g * 64 + ic];
    dst[10] = 0.f; dst[11] = 0.f;
    if (ic == 0) {
        float s = (side ? bsb : bqb)[g * 16 + j];
        for (int oc = 0; oc < 64; ++oc)
            s = fmaf(pwr[oc], b2[g * 64 + oc] + st[256 + g * 64 + oc], s);
        (side ? bfK : bfQ)[g * 16 + j] = s;
    }
}

// Grouped 3x3 conv (BN applied on the fly), bias + LeakyReLU(0.1).
// Tile 16h x 32w, 2px/thread (rows th, th+8), 32 oc per block (oh half),
// weights staged to LDS per-ic, reg-staged double buffering.
__global__ __launch_bounds__(256) void k_conv1(
    const float* __restrict__ cat, const float* __restrict__ stats,
    const float* __restrict__ w1, const float* __restrict__ b1,
    float* __restrict__ y1)
{
    int blk = blockIdx.x;
    int wt = blk & 7;   blk >>= 3;
    int ht = blk & 15;  blk >>= 4;
    int oh = blk & 1;   blk >>= 1;
    int g  = blk & 3;   blk >>= 2;
    int b  = blk;
    int tid = threadIdx.x;
    int tw = tid & 31, th = tid >> 5;
    int h = ht * 16 + th, w = wt * 32 + tw;

    __shared__ __align__(16) float tile[2][18][36];
    __shared__ __align__(16) float wb[2][32][12];

    float acc0[32], acc1[32];
    #pragma unroll
    for (int oc = 0; oc < 32; ++oc) {
        float bb = b1[g * 64 + oh * 32 + oc];
        acc0[oc] = bb; acc1[oc] = bb;
    }

    const float* catg = cat + ((size_t)b * 256 + g * 64) * 65536;
    const float* wg = w1 + (size_t)(g * 64 + oh * 32) * 576;
    int h0 = ht * 16 - 1, w0 = wt * 32 - 1;

    // loop-invariant staging geometry (18x34 = 612 halo elements)
    int r0 = tid / 34,            c0 = tid - r0 * 34;
    int i1 = tid + 256; int r1 = i1 / 34, c1 = i1 - r1 * 34;
    int i2 = tid + 512; int r2 = i2 / 34, c2 = i2 - r2 * 34;
    bool v2 = i2 < 612;
    int hh0 = h0 + r0, ww0 = w0 + c0;
    int hh1 = h0 + r1, ww1 = w0 + c1;
    int hh2 = h0 + r2, ww2 = w0 + c2;
    bool in0 = (unsigned)hh0 < 256u && (unsigned)ww0 < 256u;
    bool in1 = (unsigned)hh1 < 256u && (unsigned)ww1 < 256u;
    bool in2 = v2 && (unsigned)hh2 < 256u && (unsigned)ww2 < 256u;
    int off0 = hh0 * 256 + ww0;
    int off1 = hh1 * 256 + ww1;
    int off2 = hh2 * 256 + ww2;
    // weight staging: 32 oc x 9 = 288 elements
    int oc0 = tid / 9, k0 = tid - oc0 * 9;
    int jw1 = tid + 256; int oc1 = jw1 / 9, k1 = jw1 - oc1 * 9;
    bool wv1v = tid < 32;
    const float* wp0 = wg + (size_t)oc0 * 576 + k0;
    const float* wp1 = wg + (size_t)oc1 * 576 + k1;

    float t0, t1, t2, wv0, wv1, csn, shn;

    {   // prologue: stage ic=0 into buffer 0
        const float* plane = catg;
        csn = stats[g * 64];  shn = stats[256 + g * 64];
        t0 = in0 ? plane[off0] : 0.f;
        t1 = in1 ? plane[off1] : 0.f;
        t2 = in2 ? plane[off2] : 0.f;
        wv0 = wp0[0];
        wv1 = wv1v ? wp1[0] : 0.f;
        tile[0][r0][c0] = in0 ? fmaf(t0, csn, shn) : 0.f;
        tile[0][r1][c1] = in1 ? fmaf(t1, csn, shn) : 0.f;
        if (v2) tile[0][r2][c2] = in2 ? fmaf(t2, csn, shn) : 0.f;
        wb[0][oc0][k0] = wv0;
        if (wv1v) wb[0][oc1][k1] = wv1;
    }
    __syncthreads();

    int cur = 0;
    for (int ic = 0; ic < 64; ++ic) {
        bool pf = (ic + 1 < 64);
        if (pf) {   // issue next-ic global loads early (hide under compute)
            const float* plane = catg + (size_t)(ic + 1) * 65536;
            csn = stats[g * 64 + ic + 1];
            shn = stats[256 + g * 64 + ic + 1];
            t0 = in0 ? plane[off0] : 0.f;
            t1 = in1 ? plane[off1] : 0.f;
            t2 = in2 ? plane[off2] : 0.f;
            wv0 = wp0[(ic + 1) * 9];
            wv1 = wv1v ? wp1[(ic + 1) * 9] : 0.f;
        }
        float xv0[9], xv1[9];
        #pragma unroll
        for (int kh = 0; kh < 3; ++kh)
            #pragma unroll
            for (int kw = 0; kw < 3; ++kw) {
                xv0[kh * 3 + kw] = tile[cur][th + kh][tw + kw];
                xv1[kh * 3 + kw] = tile[cur][th + 8 + kh][tw + kw];
            }
        #pragma unroll
        for (int oc = 0; oc < 32; ++oc) {
            float4 wa = *(const float4*)&wb[cur][oc][0];
            float4 wc = *(const float4*)&wb[cur][oc][4];
            float w8 = wb[cur][oc][8];
            float s0 = acc0[oc], s1 = acc1[oc];
            s0 = fmaf(wa.x, xv0[0], s0); s1 = fmaf(wa.x, xv1[0], s1);
            s0 = fmaf(wa.y, xv0[1], s0); s1 = fmaf(wa.y, xv1[1], s1);
            s0 = fmaf(wa.z, xv0[2], s0); s1 = fmaf(wa.z, xv1[2], s1);
            s0 = fmaf(wa.w, xv0[3], s0); s1 = fmaf(wa.w, xv1[3], s1);
            s0 = fmaf(wc.x, xv0[4], s0); s1 = fmaf(wc.x, xv1[4], s1);
            s0 = fmaf(wc.y, xv0[5], s0); s1 = fmaf(wc.y, xv1[5], s1);
            s0 = fmaf(wc.z, xv0[6], s0); s1 = fmaf(wc.z, xv1[6], s1);
            s0 = fmaf(wc.w, xv0[7], s0); s1 = fmaf(wc.w, xv1[7], s1);
            s0 = fmaf(w8,  xv0[8], s0); s1 = fmaf(w8,  xv1[8], s1);
            acc0[oc] = s0; acc1[oc] = s1;
        }
        __syncthreads();
        if (pf) {
            int nb = cur ^ 1;
            tile[nb][r0][c0] = in0 ? fmaf(t0, csn, shn) : 0.f;
            tile[nb][r1][c1] = in1 ? fmaf(t1, csn, shn) : 0.f;
            if (v2) tile[nb][r2][c2] = in2 ? fmaf(t2, csn, shn) : 0.f;
            wb[nb][oc0][k0] = wv0;
            if (wv1v) wb[nb][oc1][k1] = wv1;
        }
        __syncthreads();
        cur ^= 1;
    }

    float* yp = y1 + ((size_t)b * 256 + g * 64 + oh * 32) * 65536 + h * 256 + w;
    #pragma unroll
    for (int oc = 0; oc < 32; ++oc) {
        float v0 = acc0[oc], v1 = acc1[oc];
        yp[(size_t)oc * 65536]        = v0 > 0.f ? v0 : 0.1f * v0;
        yp[(size_t)oc * 65536 + 2048] = v1 > 0.f ? v1 : 0.1f * v1;
    }
}

// Folded conv2: 16 outputs per group directly (Wtilde 3x3 over y1 + pwsc*cat),
// bias-init from bf. Tile 16h x 32w, 2px/thread, double-buffered.
__global__ __launch_bounds__(256) void k_conv2f(
    const float* __restrict__ y1, const float* __restrict__ cat,
    const float* __restrict__ Wf, const float* __restrict__ bf,
    float* __restrict__ Qout)
{
    int blk = blockIdx.x;
    int wt = blk & 7;   blk >>= 3;
    int ht = blk & 15;  blk >>= 4;
    int g  = blk & 3;   blk >>= 2;
    int b  = blk;
    int tid = threadIdx.x;
    int tw = tid & 31, th = tid >> 5;
    int h = ht * 16 + th, w = wt * 32 + tw;

    __shared__ __align__(16) float tile[2][18][36];
    __shared__ __align__(16) float wb[2][16][12];

    float acc0[16], acc1[16];
    #pragma unroll
    for (int j = 0; j < 16; ++j) {
        float bb = bf[g * 16 + j];
        acc0[j] = bb; acc1[j] = bb;
    }

    const float* yg = y1 + ((size_t)b * 256 + g * 64) * 65536;
    const float* catp = cat + ((size_t)b * 256 + g * 64) * 65536 + h * 256 + w;
    const float* wfg = Wf + (size_t)(g * 64) * 192;
    int h0 = ht * 16 - 1, w0 = wt * 32 - 1;

    int r0 = tid / 34,            c0 = tid - r0 * 34;
    int i1 = tid + 256; int r1 = i1 / 34, c1 = i1 - r1 * 34;
    int i2 = tid + 512; int r2 = i2 / 34, c2 = i2 - r2 * 34;
    bool v2 = i2 < 612;
    int hh0 = h0 + r0, ww0 = w0 + c0;
    int hh1 = h0 + r1, ww1 = w0 + c1;
    int hh2 = h0 + r2, ww2 = w0 + c2;
    bool in0 = (unsigned)hh0 < 256u && (unsigned)ww0 < 256u;
    bool in1 = (unsigned)hh1 < 256u && (unsigned)ww1 < 256u;
    bool in2 = v2 && (unsigned)hh2 < 256u && (unsigned)ww2 < 256u;
    int off0 = hh0 * 256 + ww0;
    int off1 = hh1 * 256 + ww1;
    int off2 = hh2 * 256 + ww2;
    int jw = tid / 12, kw2 = tid - jw * 12;   // Wf block: 16x12 = 192
    bool wv = tid < 192;

    float t0, t1, t2, wvv, cv0, cv1, ncv0, ncv1;

    {   // prologue ic=0
        const float* plane = yg;
        t0 = in0 ? plane[off0] : 0.f;
        t1 = in1 ? plane[off1] : 0.f;
        t2 = in2 ? plane[off2] : 0.f;
        wvv = wv ? wfg[tid] : 0.f;
        cv0 = catp[0];
        cv1 = catp[2048];
        tile[0][r0][c0] = t0;
        tile[0][r1][c1] = t1;
        if (v2) tile[0][r2][c2] = t2;
        if (wv) wb[0][jw][kw2] = wvv;
    }
    __syncthreads();

    int cur = 0;
    for (int ic = 0; ic < 64; ++ic) {
        bool pf = (ic + 1 < 64);
        if (pf) {
            const float* plane = yg + (size_t)(ic + 1) * 65536;
            t0 = in0 ? plane[off0] : 0.f;
            t1 = in1 ? plane[off1] : 0.f;
            t2 = in2 ? plane[off2] : 0.f;
            wvv = wv ? wfg[(size_t)(ic + 1) * 192 + tid] : 0.f;
            ncv0 = catp[(size_t)(ic + 1) * 65536];
            ncv1 = catp[(size_t)(ic + 1) * 65536 + 2048];
        }
        float xv0[9], xv1[9];
        #pragma unroll
        for (int kh = 0; kh < 3; ++kh)
            #pragma unroll
            for (int kw = 0; kw < 3; ++kw) {
                xv0[kh * 3 + kw] = tile[cur][th + kh][tw + kw];
                xv1[kh * 3 + kw] = tile[cur][th + 8 + kh][tw + kw];
            }
        #pragma unroll
        for (int j = 0; j < 16; ++j) {
            float4 wa = *(const float4*)&wb[cur][j][0];
            float4 wc = *(const float4*)&wb[cur][j][4];
            float w8  = wb[cur][j][8];
            float pws = wb[cur][j][9];
            float s0 = acc0[j], s1 = acc1[j];
            s0 = fmaf(wa.x, xv0[0], s0); s1 = fmaf(wa.x, xv1[0], s1);
            s0 = fmaf(wa.y, xv0[1], s0); s1 = fmaf(wa.y, xv1[1], s1);
            s0 = fmaf(wa.z, xv0[2], s0); s1 = fmaf(wa.z, xv1[2], s1);
            s0 = fmaf(wa.w, xv0[3], s0); s1 = fmaf(wa.w, xv1[3], s1);
            s0 = fmaf(wc.x, xv0[4], s0); s1 = fmaf(wc.x, xv1[4], s1);
            s0 = fmaf(wc.y, xv0[5], s0); s1 = fmaf(wc.y, xv1[5], s1);
            s0 = fmaf(wc.z, xv0[6], s0); s1 = fmaf(wc.z, xv1[6], s1);
            s0 = fmaf(wc.w, xv0[7], s0); s1 = fmaf(wc.w, xv1[7], s1);
            s0 = fmaf(w8,  xv0[8], s0); s1 = fmaf(w8,  xv1[8], s1);
            s0 = fmaf(pws, cv0, s0);    s1 = fmaf(pws, cv1, s1);
            acc0[j] = s0; acc1[j] = s1;
        }
        __syncthreads();
        if (pf) {
            int nb = cur ^ 1;
            tile[nb][r0][c0] = t0;
            tile[nb][r1][c1] = t1;
            if (v2) tile[nb][r2][c2] = t2;
            if (wv) wb[nb][jw][kw2] = wvv;
            cv0 = ncv0; cv1 = ncv1;
        }
        __syncthreads();
        cur ^= 1;
    }

    float* qp = Qout + ((size_t)b * 64 + g * 16) * 65536 + h * 256 + w;
    #pragma unroll
    for (int j = 0; j < 16; ++j) {
        qp[(size_t)j * 65536]        = acc0[j];
        qp[(size_t)j * 65536 + 2048] = acc1[j];
    }
}

// Horizontal disparity gathers, output in [b,h,w,c] layout (flat-index ready).
__global__ __launch_bounds__(256) void k_gather(
    const float* __restrict__ Kb, const float* __restrict__ Qb,
    const float* __restrict__ xr, const float* __restrict__ xl,
    const int* __restrict__ dl, const int* __restrict__ dr,
    float* __restrict__ GK, float* __restrict__ GQ,
    float* __restrict__ Gxr, float* __restrict__ Gxl)
{
    int blk = blockIdx.x;
    int h = blk & 255; blk >>= 8;
    int b = blk & 1;   blk >>= 1;
    int sel = blk;
    const float* src; float* dst; const int* dd; int r2l;
    if (sel == 0)      { src = Kb; dst = GK;  dd = dl; r2l = 1; }
    else if (sel == 1) { src = Qb; dst = GQ;  dd = dr; r2l = 0; }
    else if (sel == 2) { src = xr; dst = Gxr; dd = dl; r2l = 1; }
    else               { src = xl; dst = Gxl; dd = dr; r2l = 0; }
    const int* drow = dd + ((size_t)b * 256 + h) * 256;
    const float* sp = src + (size_t)b * 4194304 + h * 256;
    float* dp = dst + ((size_t)b * 256 + h) * 16384;
    int tid = threadIdx.x;
    for (int i = tid; i < 16384; i += 256) {
        int w = i >> 6, cc = i & 63;
        int d = drow[w];
        int wi = r2l ? (w - d < 0 ? 0 : w - d) : (w + d > 255 ? 255 : w + d);
        dp[i] = sp[(size_t)cc * 65536 + wi];
    }
}

// Per-window attention: score = patchA @ centered(sel)^T, softmax, @ x_sel,
// unpatchify + masked residual. One block per (dir, b, hn, wn).
__global__ __launch_bounds__(256) void k_attn(
    const float* __restrict__ Qb, const float* __restrict__ Kb,
    const float* __restrict__ GK, const float* __restrict__ GQ,
    const float* __restrict__ Gxr, const float* __restrict__ Gxl,
    const float* __restrict__ xl, const float* __restrict__ xr,
    const int* __restrict__ dl, const int* __restrict__ dr,
    float* __restrict__ out)
{
    int blk = blockIdx.x;
    int wn = blk & 31; blk >>= 5;
    int hn = blk & 31; blk >>= 5;
    int b  = blk & 1;  blk >>= 1;
    int dir = blk;  // 0: out_left, 1: out_right

    const float* Amat = dir ? Kb : Qb;
    const float* Bg   = dir ? GQ : GK;
    const float* Xg   = dir ? Gxl : Gxr;
    const float* base = dir ? xr : xl;
    const int*  dd    = dir ? dr : dl;
    float* op = out + (size_t)dir * 8388608;

    __shared__ float A[64][65];
    __shared__ float Bm[64][65];
    __shared__ float S[64][65];
    __shared__ float rowsum[64];
    __shared__ float pmean[8];

    int tid = threadIdx.x;
    size_t abase = (size_t)b * 4194304 + (size_t)(hn * 8) * 256 + wn * 8;
    for (int i = tid; i < 4096; i += 256) {
        int cc = i >> 6, p1 = i & 63;
        A[p1][cc] = Amat[abase + (size_t)cc * 65536 + (p1 >> 3) * 256 + (p1 & 7)];
    }
    size_t gbase = (size_t)b * 4194304 + hn * 2048 + wn * 8;
    for (int i = tid; i < 4096; i += 256) {
        int cc = i >> 6, p2 = i & 63;
        Bm[p2][cc] = Bg[gbase + (size_t)cc * 65536 + (p2 >> 3) * 256 + (p2 & 7)];
    }
    __syncthreads();
    if (tid < 64) {
        float s = 0.f;
        #pragma unroll 8
        for (int cc = 0; cc < 64; ++cc) s += Bm[tid][cc];
        rowsum[tid] = s;
    }
    __syncthreads();
    if (tid < 8) {
        float s = 0.f;
        #pragma unroll
        for (int q = 0; q < 8; ++q) s += rowsum[tid * 8 + q];
        pmean[tid] = s * (1.f / 512.f);
    }
    __syncthreads();
    for (int i = tid; i < 4096; i += 256) {
        int p2 = i >> 6, cc = i & 63;
        Bm[p2][cc] -= pmean[p2 >> 3];
    }
    __syncthreads();

    int tp = (tid >> 4) << 2;
    int tc = (tid & 15) << 2;
    {   // S = A @ Bm^T
        float accs[4][4] = {};
        for (int cc = 0; cc < 64; ++cc) {
            float av[4], bv[4];
            #pragma unroll
            for (int i = 0; i < 4; ++i) av[i] = A[tp + i][cc];
            #pragma unroll
            for (int j = 0; j < 4; ++j) bv[j] = Bm[tc + j][cc];
            #pragma unroll
            for (int i = 0; i < 4; ++i)
                #pragma unroll
                for (int j = 0; j < 4; ++j)
                    accs[i][j] = fmaf(av[i], bv[j], accs[i][j]);
        }
        #pragma unroll
        for (int i = 0; i < 4; ++i)
            #pragma unroll
            for (int j = 0; j < 4; ++j)
                S[tp + i][tc + j] = accs[i][j];
    }
    __syncthreads();
    if (tid < 64) {
        float m = -3.0e38f;
        #pragma unroll 8
        for (int j = 0; j < 64; ++j) m = fmaxf(m, S[tid][j]);
        float ssum = 0.f;
        #pragma unroll 8
        for (int j = 0; j < 64; ++j) {
            float e = __expf(S[tid][j] - m);
            S[tid][j] = e; ssum += e;
        }
        float inv = 1.f / ssum;
        #pragma unroll 8
        for (int j = 0; j < 64; ++j) S[tid][j] *= inv;
    }
    __syncthreads();
    for (int i = tid; i < 4096; i += 256) {
        int cc = i >> 6, p2 = i & 63;
        Bm[p2][cc] = Xg[gbase + (size_t)cc * 65536 + (p2 >> 3) * 256 + (p2 & 7)];
    }
    __syncthreads();
    {   // out = S @ X, unpatchify, masked residual
        float accs[4][4] = {};
        for (int p2 = 0; p2 < 64; ++p2) {
            float sv[4], xv[4];
            #pragma unroll
            for (int i = 0; i < 4; ++i) sv[i] = S[tp + i][p2];
            #pragma unroll
            for (int j = 0; j < 4; ++j) xv[j] = Bm[p2][tc + j];
            #pragma unroll
            for (int i = 0; i < 4; ++i)
                #pragma unroll
                for (int j = 0; j < 4; ++j)
                    accs[i][j] = fmaf(sv[i], xv[j], accs[i][j]);
        }
        #pragma unroll
        for (int i = 0; i < 4; ++i) {
            int p1 = tp + i;
            int h1 = hn * 8 + (p1 >> 3), w1 = wn * 8 + (p1 & 7);
            int d = dd[(size_t)b * 65536 + h1 * 256 + w1];
            float msk = dir ? ((w1 + d <= 255) ? 1.f : 0.f)
                            : ((w1 - d >= 0) ? 1.f : 0.f);
            #pragma unroll
            for (int j = 0; j < 4; ++j) {
                int ch = tc + j;
                size_t o = (size_t)b * 4194304 + (size_t)ch * 65536 + (size_t)h1 * 256 + w1;
                op[o] = fmaf(accs[i][j], msk, base[o]);
            }
        }
    }
}

extern "C" void kernel_launch(void* const* d_in, const int* in_sizes, int n_in,
                              void* d_out, int out_size, void* d_ws, size_t ws_size,
                              hipStream_t stream) {
    (void)in_sizes; (void)n_in; (void)out_size; (void)ws_size;
    const float* x_left  = (const float*)d_in[0];
    const float* x_right = (const float*)d_in[1];
    const float* cat_l   = (const float*)d_in[2];
    const float* cat_r   = (const float*)d_in[3];
    const int*   d_left  = (const int*)d_in[4];
    const int*   d_right = (const int*)d_in[5];
    const float* gamma   = (const float*)d_in[6];
    const float* beta    = (const float*)d_in[7];
    const float* rb_w1   = (const float*)d_in[8];
    const float* rb_b1   = (const float*)d_in[9];
    const float* rb_w2   = (const float*)d_in[10];
    const float* rb_b2   = (const float*)d_in[11];
    const float* bq_w    = (const float*)d_in[12];
    const float* bq_b    = (const float*)d_in[13];
    const float* bs_w    = (const float*)d_in[14];
    const float* bs_b    = (const float*)d_in[15];
    float* out = (float*)d_out;
    float* ws  = (float*)d_ws;

    float* y1    = ws;               // 33,554,432 floats (reused per side)
    float* GK    = ws;               // alias after y1 is dead
    float* GQ    = ws + 8388608;
    float* Gxr   = ws + 16777216;
    float* Gxl   = ws + 25165824;
    float* Qb    = ws + 33554432;
    float* Kb    = ws + 41943040;
    float* stats = ws + 50331648;    // [2][scale 256 | shift 256]
    // fold scratch: WfQ/bfQ in dead Kb region (Kb written by last conv2f);
    // WfK/bfK in d_out (untouched until k_attn).
    float* WfQ = Kb;                 // 49152 floats
    float* bfQ = Kb + 49152;         // 64 floats
    float* WfK = out;                // 49152 floats
    float* bfK = out + 49152;        // 64 floats

    k_bnstats<<<512, 256, 0, stream>>>(cat_l, cat_r, gamma, beta, stats);
    k_fold<<<32, 256, 0, stream>>>(rb_w2, rb_b2, bq_w, bq_b, bs_w, bs_b, stats,
                                   WfQ, bfQ, WfK, bfK);
    k_conv1<<<2048, 256, 0, stream>>>(cat_l, stats, rb_w1, rb_b1, y1);
    k_conv2f<<<1024, 256, 0, stream>>>(y1, cat_l, WfQ, bfQ, Qb);
    k_conv1<<<2048, 256, 0, stream>>>(cat_r, stats + 512, rb_w1, rb_b1, y1);
    k_conv2f<<<1024, 256, 0, stream>>>(y1, cat_r, WfK, bfK, Kb);
    k_gather<<<2048, 256, 0, stream>>>(Kb, Qb, x_right, x_left, d_left, d_right,
                                       GK, GQ, Gxr, Gxl);
    k_attn<<<4096, 256, 0, stream>>>(Qb, Kb, GK, GQ, Gxr, Gxl,
                                     x_left, x_right, d_left, d_right, out);
}